// Round 6
// baseline (1102.410 us; speedup 1.0000x reference)
//
#include <hip/hip_runtime.h>

// LinearTPReadOut: out[n] = w_tp/(128*sqrt(3)) * sum_i a_i*b_i,
//   a_i = sum_u x[n, 128+3u+i]*w_lin[u,0],  b_i = sum_u x[n, 128+3u+i]*w_lin[u,1]
// N=200000 rows of 1152 floats; only cols [128,512) touched (1536B per row).
// Roofline: 200000*1536B = 307 MB read -> ~50-80 us at achievable BW. Memory-bound.
//
// Structure (v2): no LDS, no __syncthreads, persistent grid-stride.
//  - 16 lanes per row-group; lane t owns the CONTIGUOUS floats [24t, 24t+24)
//    of the 384-float chunk, so position p = 24t+q gives i = q%3 (compile-time)
//    and u = 8t + q/3 (weight regs preloaded once per lane). 12x float2 loads
//    (8B-aligned: 4608*row + 512 + 96*t).
//  - Grid = 2048 blocks x 256 thr = 8 blocks/CU (max waves), weights loaded
//    once, ~6 rows per group via stride loop. Per row: 12 loads, 48 FMA,
//    24 shfl_xor, 1 store. Prior version paid LDS round-trip (16-way bank
//    conflict on compute reads) + sync + per-16-rows setup across 12500 blocks.

#define ROW_STRIDE 1152
#define OFF 128

__global__ __launch_bounds__(256) void lintp_kernel(
    const float* __restrict__ x,
    const float* __restrict__ w_lin,
    const float* __restrict__ w_tp,
    float* __restrict__ out,
    int n)
{
    const int tid = threadIdx.x;
    const int t   = tid & 15;        // lane within 16-lane group
    const int g   = tid >> 4;        // group index within block

    // Preload lane-invariant weights once: u = 8t..8t+7 -> w_lin flat [16t..16t+15].
    float w0[8], w1[8];
    const float4* wv = (const float4*)(w_lin + 16 * t);
#pragma unroll
    for (int k = 0; k < 4; ++k) {
        float4 w = wv[k];
        w0[2 * k]     = w.x;  w1[2 * k]     = w.y;
        w0[2 * k + 1] = w.z;  w1[2 * k + 1] = w.w;
    }

    const float scale = w_tp[0] * (1.0f / (128.0f * 1.7320508075688772f));

    const int group   = blockIdx.x * 16 + g;
    const int ngroups = gridDim.x * 16;

    for (int row = group; row < n; row += ngroups) {
        // Lane t reads its contiguous 24 floats: byte addr 4608*row + 512 + 96*t
        // (8B-aligned) as 12x float2.
        const float2* xp = (const float2*)(x + (size_t)row * ROW_STRIDE + OFF) + 12 * t;
        float2 d[12];
#pragma unroll
        for (int m = 0; m < 12; ++m) d[m] = xp[m];   // 12 loads in flight

        float a0 = 0.f, a1 = 0.f, a2 = 0.f, b0 = 0.f, b1 = 0.f, b2 = 0.f;
#pragma unroll
        for (int m = 0; m < 12; ++m) {
            const float vx = d[m].x;
            const float vy = d[m].y;
            {
                const int q = 2 * m;         // 0..22 even
                const int i = q % 3;         // compile-time
                const int u = q / 3;         // 0..7, compile-time
                if (i == 0)      { a0 += vx * w0[u]; b0 += vx * w1[u]; }
                else if (i == 1) { a1 += vx * w0[u]; b1 += vx * w1[u]; }
                else             { a2 += vx * w0[u]; b2 += vx * w1[u]; }
            }
            {
                const int q = 2 * m + 1;     // 1..23 odd
                const int i = q % 3;
                const int u = q / 3;
                if (i == 0)      { a0 += vy * w0[u]; b0 += vy * w1[u]; }
                else if (i == 1) { a1 += vy * w0[u]; b1 += vy * w1[u]; }
                else             { a2 += vy * w0[u]; b2 += vy * w1[u]; }
            }
        }

        // Butterfly reduce within the 16-lane group (masks < 16 stay in-group).
#pragma unroll
        for (int m = 1; m <= 8; m <<= 1) {
            a0 += __shfl_xor(a0, m); a1 += __shfl_xor(a1, m); a2 += __shfl_xor(a2, m);
            b0 += __shfl_xor(b0, m); b1 += __shfl_xor(b1, m); b2 += __shfl_xor(b2, m);
        }

        if (t == 0) {
            out[row] = scale * (a0 * b0 + a1 * b1 + a2 * b2);
        }
    }
}

extern "C" void kernel_launch(void* const* d_in, const int* in_sizes, int n_in,
                              void* d_out, int out_size, void* d_ws, size_t ws_size,
                              hipStream_t stream) {
    const float* x     = (const float*)d_in[0];
    const float* w_lin = (const float*)d_in[1];
    const float* w_tp  = (const float*)d_in[2];
    float* out = (float*)d_out;

    const int n = in_sizes[0] / ROW_STRIDE;          // 200000
    int blocks = (n + 15) / 16;
    if (blocks > 2048) blocks = 2048;                // 8 blocks/CU, grid-stride
    lintp_kernel<<<blocks, 256, 0, stream>>>(x, w_lin, w_tp, out, n);
}

// Round 8
// 1020.653 us; speedup vs baseline: 1.0801x; 1.0801x over previous
//
#include <hip/hip_runtime.h>

// LinearTPReadOut: out[n] = w_tp/(128*sqrt(3)) * sum_i a_i*b_i,
//   a_i = sum_u x[n, 128+3u+i]*w_lin[u,0],  b_i = sum_u x[n, 128+3u+i]*w_lin[u,1]
// N=200000 rows of 1152 floats; only cols [128,512) touched (1536B per row).
// Roofline: 200000*1536B = 307 MB read -> ~50-80 us floor. Memory-bound.
//
// v3: one-shot blocks (v1's MLP) + register-direct compute (v2's no-LDS path)
//     + float4 loads (96t bytes is 16B-aligned, so lane-contiguous 24-float
//     slices load as 6x dwordx4 — v2's float2 downgrade was unnecessary).
//  - 16 groups x 16 lanes per block, one row per group, 12500 blocks.
//  - Lane t owns contiguous floats [24t, 24t+24) of the row chunk:
//    p = 24t+q -> i = q%3, u = 8t + q/3, all compile-time per lane.
//  - Per thread: 6 float4 loads (in flight together), 48 FMA, 24 shfl, 1 store.
//    No LDS, no __syncthreads, no bank conflicts, no serial row loop.

#define ROW_STRIDE 1152
#define OFF 128

__global__ __launch_bounds__(256) void lintp_kernel(
    const float* __restrict__ x,
    const float* __restrict__ w_lin,
    const float* __restrict__ w_tp,
    float* __restrict__ out,
    int n)
{
    const int tid = threadIdx.x;
    const int t   = tid & 15;        // lane within 16-lane group
    const int g   = tid >> 4;        // group = local row

    const int row  = blockIdx.x * 16 + g;
    const int rowc = (row < n) ? row : (n - 1);      // clamp (n%16==0 normally)

    // Lane t's contiguous 24 floats: byte addr 4608*row + 512 + 96*t (16B-aligned).
    const float4* xp = (const float4*)(x + (size_t)rowc * ROW_STRIDE + OFF + 24 * t);
    float4 d[6];
#pragma unroll
    for (int k = 0; k < 6; ++k) d[k] = xp[k];        // 6 loads in flight

    // Lane-invariant weights: u = 8t..8t+7 -> w_lin flat [16t..16t+15].
    float w0[8], w1[8];
    const float4* wv = (const float4*)(w_lin + 16 * t);
#pragma unroll
    for (int k = 0; k < 4; ++k) {
        float4 w = wv[k];
        w0[2 * k]     = w.x;  w1[2 * k]     = w.y;
        w0[2 * k + 1] = w.z;  w1[2 * k + 1] = w.w;
    }

    float a0 = 0.f, a1 = 0.f, a2 = 0.f, b0 = 0.f, b1 = 0.f, b2 = 0.f;
#pragma unroll
    for (int k = 0; k < 6; ++k) {
        const float cc[4] = {d[k].x, d[k].y, d[k].z, d[k].w};
#pragma unroll
        for (int j = 0; j < 4; ++j) {
            const int q = 4 * k + j;     // 0..23, compile-time
            const int i = q % 3;
            const int u = q / 3;         // 0..7
            const float av = cc[j];
            if (i == 0)      { a0 += av * w0[u]; b0 += av * w1[u]; }
            else if (i == 1) { a1 += av * w0[u]; b1 += av * w1[u]; }
            else             { a2 += av * w0[u]; b2 += av * w1[u]; }
        }
    }

    // Butterfly reduce within the 16-lane group (masks < 16 stay in-group).
#pragma unroll
    for (int m = 1; m <= 8; m <<= 1) {
        a0 += __shfl_xor(a0, m); a1 += __shfl_xor(a1, m); a2 += __shfl_xor(a2, m);
        b0 += __shfl_xor(b0, m); b1 += __shfl_xor(b1, m); b2 += __shfl_xor(b2, m);
    }

    if (t == 0 && row < n) {
        const float scale = w_tp[0] * (1.0f / (128.0f * 1.7320508075688772f));
        out[row] = scale * (a0 * b0 + a1 * b1 + a2 * b2);
    }
}

extern "C" void kernel_launch(void* const* d_in, const int* in_sizes, int n_in,
                              void* d_out, int out_size, void* d_ws, size_t ws_size,
                              hipStream_t stream) {
    const float* x     = (const float*)d_in[0];
    const float* w_lin = (const float*)d_in[1];
    const float* w_tp  = (const float*)d_in[2];
    float* out = (float*)d_out;

    const int n = in_sizes[0] / ROW_STRIDE;          // 200000
    const int blocks = (n + 15) / 16;                // 16 rows / 256-thread block
    lintp_kernel<<<blocks, 256, 0, stream>>>(x, w_lin, w_tp, out, n);
}